// Round 7
// baseline (156.481 us; speedup 1.0000x reference)
//
#include <hip/hip_runtime.h>
#include <hip/hip_bf16.h>
#include <math.h>

#define HS 64
#define NE 128
#define TSEQ 2048

typedef short s8v __attribute__((ext_vector_type(8)));   // 8 bf16 (4 VGPRs) MFMA A/B frag
typedef float f4v __attribute__((ext_vector_type(4)));   // 4 fp32 MFMA C/D frag

__device__ __forceinline__ unsigned short f2bf(float f) {
    unsigned int u = __float_as_uint(f);
    u += 0x7FFFu + ((u >> 16) & 1u);   // RNE (no NaN inputs here)
    return (unsigned short)(u >> 16);
}

// packed f32x2 -> bf16x2
__device__ __forceinline__ unsigned int pkbf(float a, float b) {
    union { __hip_bfloat162 h; unsigned int u; } cv;
    cv.h = __float22bfloat162_rn(make_float2(a, b));
    return cv.u;
}

__device__ __forceinline__ s8v mk_s8v(unsigned int a, unsigned int b,
                                      unsigned int c, unsigned int d) {
    union { unsigned int u[4]; s8v v; } cv;
    cv.u[0] = a; cv.u[1] = b; cv.u[2] = c; cv.u[3] = d;
    return cv.v;
}

// ---------------- W -> bf16, transposed wt[mat][n][k], q pre-scaled ----------------
__global__ __launch_bounds__(256) void wconv(
    const float* __restrict__ Wq, const float* __restrict__ Wk,
    const float* __restrict__ Wv, unsigned short* __restrict__ wt)
{
    const int o0 = (blockIdx.x * 256 + threadIdx.x) * 2;   // 24576 elems total
    const int mat = o0 >> 13;
    const int n = (o0 >> 7) & 63;
    const int k = o0 & 127;        // even
    const float* W = (mat == 0) ? Wq : (mat == 1) ? Wk : Wv;
    const float s = (mat == 0) ? 0.18033688f : 1.0f;   // 64^-0.5 * log2(e)
    unsigned int lo = f2bf(W[k * HS + n] * s);
    unsigned int hi = f2bf(W[(k + 1) * HS + n] * s);
    *(unsigned int*)(wt + o0) = lo | (hi << 16);
}

// ---------------- QKV projection: lean single-wave blocks ----------------
// 6144 blocks x 64 thr: block = (16 x-rows, one of q/k/v). 16 W-frag b128
// loads (L2-resident) + 16 MFMA. q/k transpose via wave-local LDS; v packed
// dim-major directly from C-frags. 24 blocks/CU -> latency hidden.
__global__ __launch_bounds__(64) void qkv(
    const float* __restrict__ x, const unsigned short* __restrict__ wt,
    const float* __restrict__ bq, const float* __restrict__ bk,
    const float* __restrict__ bv,
    unsigned short* __restrict__ qo, unsigned short* __restrict__ ko,
    unsigned short* __restrict__ vt)
{
    __shared__ __align__(16) float Tt[16 * 68];   // 4.3 KB

    const int tid = threadIdx.x;
    const int quad = tid >> 4;
    const int li = tid & 15;
    const int n = blockIdx.x;
    const int rb = n / 3;                // row-block 0..2047 (consecutive blocks
    const int mat = n - rb * 3;          //  share x rows -> L2/L3 locality)
    const size_t r0 = (size_t)rb * 16;

    // A-frags: x rows (fp32 -> bf16): A[m=li][k=quad*8+j] per ks
    s8v a[4];
    const float* xr = x + (r0 + li) * NE + quad * 8;
#pragma unroll
    for (int ks = 0; ks < 4; ++ks) {
        float4 f0 = *(const float4*)(xr + ks * 32);
        float4 f1 = *(const float4*)(xr + ks * 32 + 4);
        a[ks] = mk_s8v(pkbf(f0.x, f0.y), pkbf(f0.z, f0.w),
                       pkbf(f1.x, f1.y), pkbf(f1.z, f1.w));
    }

    f4v acc[4];
#pragma unroll
    for (int nt = 0; nt < 4; ++nt) acc[nt] = (f4v){0.f, 0.f, 0.f, 0.f};

    const unsigned short* wm = wt + mat * (64 * NE);
#pragma unroll
    for (int nt = 0; nt < 4; ++nt) {
        const unsigned short* wr = wm + (nt * 16 + li) * NE + quad * 8;
#pragma unroll
        for (int ks = 0; ks < 4; ++ks) {
            s8v bfr = *(const s8v*)(wr + ks * 32);
            acc[nt] = __builtin_amdgcn_mfma_f32_16x16x32_bf16(a[ks], bfr, acc[nt], 0, 0, 0);
        }
    }

    if (mat == 2) {
        // v: C rows (=t) consecutive per lane -> one 8B store per ntile
        const size_t bidx = r0 >> 11;
        const size_t trow = (r0 & 2047) + quad * 4;
#pragma unroll
        for (int nt = 0; nt < 4; ++nt) {
            const float bias = bv[nt * 16 + li];
            *(uint2*)(vt + (bidx * HS + nt * 16 + li) * TSEQ + trow) =
                make_uint2(pkbf(acc[nt][0] + bias, acc[nt][1] + bias),
                           pkbf(acc[nt][2] + bias, acc[nt][3] + bias));
        }
    } else {
        // q/k: transpose through LDS (stride 68 -> 2-way banks = free)
        const float* barr = mat ? bk : bq;
        const float bsc = mat ? 1.0f : 0.18033688f;   // q bias scaled like Wq
#pragma unroll
        for (int nt = 0; nt < 4; ++nt) {
            const float bias = barr[nt * 16 + li] * bsc;
#pragma unroll
            for (int r = 0; r < 4; ++r)
                Tt[(quad * 4 + r) * 68 + nt * 16 + li] = acc[nt][r] + bias;
        }
        __syncthreads();   // single wave: cheap; guarantees LDS visibility
        const int row = tid >> 2;
        const int seg = tid & 3;
        const float* src = &Tt[row * 68 + seg * 16];
        float4 f0 = *(const float4*)src;
        float4 f1 = *(const float4*)(src + 4);
        float4 f2 = *(const float4*)(src + 8);
        float4 f3 = *(const float4*)(src + 12);
        s8v d0 = mk_s8v(pkbf(f0.x, f0.y), pkbf(f0.z, f0.w), pkbf(f1.x, f1.y), pkbf(f1.z, f1.w));
        s8v d1 = mk_s8v(pkbf(f2.x, f2.y), pkbf(f2.z, f2.w), pkbf(f3.x, f3.y), pkbf(f3.z, f3.w));
        unsigned short* dst = (mat ? ko : qo) + (r0 + row) * HS + seg * 16;
        *(s8v*)dst = d0;
        *(s8v*)(dst + 8) = d1;
    }
}

// ---------------- Flash attention: key-split waves + block reduction ----------------
// 2048 blocks x 4 waves. Block = one 16-row q-tile (qi); wave w handles key
// tiles tl = w, w+4, ... (valid because no-max exp2 softmax is additive over
// keys). Partial O (C-layout fp32) + partial lsum reduced across the 4 waves
// through LDS at the end. P round-trip uses a 16B-granule-transposed layout:
// reads are ds_read_b128 at granule==lane (0 conflicts), writes 256B-contig.
__global__ __launch_bounds__(256) void attn(
    const unsigned short* __restrict__ qb,
    const unsigned short* __restrict__ kb,
    const unsigned short* __restrict__ vtb,
    float* __restrict__ out)
{
    __shared__ __align__(16) float Or[4 * 1088];   // [wave][16][68] fp32; P aliases head
    __shared__ float Ls[4][16];

    const int tid = threadIdx.x;
    const int w = tid >> 6;
    const int lane = tid & 63;
    const int quad = lane >> 4;
    const int li = lane & 15;

    const int n = blockIdx.x;
    const int b = n & 15;
    const int qi = 127 - (n >> 4);        // largest q-tiles dispatched first
    const size_t base = (size_t)b * TSEQ;
    const int qrow = (qi << 4) + li;
    const int nt64 = (qi >> 2) + 1;

    // Q B-frags (regs, once); scale*log2e pre-folded
    const unsigned short* qrp = qb + (base + qrow) * HS + quad * 8;
    s8v qf0 = *(const s8v*)qrp;
    s8v qf1 = *(const s8v*)(qrp + 32);

    const unsigned short* kl = kb + (base + li) * HS + quad * 8;
    const unsigned short* vl = vtb + ((size_t)b * HS + li) * TSEQ + quad * 8;

    f4v c_o[4];
#pragma unroll
    for (int f = 0; f < 4; ++f) c_o[f] = (f4v){0.f, 0.f, 0.f, 0.f};
    float lsum = 0.f;

    // wave-private P region: granule-transposed [key-chunk c][row li], 16B granules
    char* pbase = (char*)&Or[w * 1088];

    // preload K tile tl=w (always in-bounds; wasted if w >= nt64)
    s8v kc0[4], kc1[4];
    {
        const unsigned short* kt0 = kl + (size_t)(w << 6) * HS;
#pragma unroll
        for (int kt = 0; kt < 4; ++kt) {
            const unsigned short* p = kt0 + kt * 16 * HS;
            kc0[kt] = *(const s8v*)p;
            kc1[kt] = *(const s8v*)(p + 32);
        }
    }

    for (int tl = w; tl < nt64; tl += 4) {
        const int s0 = tl << 6;
        const bool last = (tl == nt64 - 1);

        // V(t): issued now, consumed after softmax
        s8v vv0[4], vv1[4];
#pragma unroll
        for (int f = 0; f < 4; ++f) {
            const unsigned short* vp = vl + f * 16 * TSEQ + s0;
            vv0[f] = *(const s8v*)vp;
            vv1[f] = *(const s8v*)(vp + 32);
        }

        // S^T = K · Q^T (consumes kc)
        f4v cst[4];
#pragma unroll
        for (int kt = 0; kt < 4; ++kt) {
            f4v z = (f4v){0.f, 0.f, 0.f, 0.f};
            z = __builtin_amdgcn_mfma_f32_16x16x32_bf16(kc0[kt], qf0, z, 0, 0, 0);
            cst[kt] = __builtin_amdgcn_mfma_f32_16x16x32_bf16(kc1[kt], qf1, z, 0, 0, 0);
        }

        // K(tl+4) register prefetch
        if (tl + 4 < nt64) {
            const unsigned short* kn = kl + (size_t)(s0 + 256) * HS;
#pragma unroll
            for (int kt = 0; kt < 4; ++kt) {
                const unsigned short* p = kn + kt * 16 * HS;
                kc0[kt] = *(const s8v*)p;
                kc1[kt] = *(const s8v*)(p + 32);
            }
        }

        // softmax (exp2 domain, no max subtraction; causal mask on last tile)
        float pr[4][4];
        float rs = 0.f;
#pragma unroll
        for (int kt = 0; kt < 4; ++kt) {
            if (last) {
                const int key0 = s0 + kt * 16 + quad * 4;
#pragma unroll
                for (int rr = 0; rr < 4; ++rr)
                    if (key0 + rr > qrow) cst[kt][rr] = -INFINITY;
            }
#pragma unroll
            for (int rr = 0; rr < 4; ++rr) {
                pr[kt][rr] = exp2f(cst[kt][rr]);
                rs += pr[kt][rr];
            }
        }
        lsum += rs;

        // P -> LDS, granule-transposed: key kt*16+quad*4 -> granule kt*2+(quad>>1),
        // half (quad&1); write = 256B contiguous per kt (conflict-free)
#pragma unroll
        for (int kt = 0; kt < 4; ++kt) {
            *(uint2*)(pbase + (kt * 2 + (quad >> 1)) * 256 + li * 16 + (quad & 1) * 8) =
                make_uint2(pkbf(pr[kt][0], pr[kt][1]), pkbf(pr[kt][2], pr[kt][3]));
        }
        // B-frag reads: granule quad*16+li == lane (linear, 0 conflicts)
        s8v pf0 = *(const s8v*)(pbase + lane * 16);
        s8v pf1 = *(const s8v*)(pbase + 1024 + lane * 16);

        // O^T += V^T · P^T
#pragma unroll
        for (int f = 0; f < 4; ++f) {
            c_o[f] = __builtin_amdgcn_mfma_f32_16x16x32_bf16(vv0[f], pf0, c_o[f], 0, 0, 0);
            c_o[f] = __builtin_amdgcn_mfma_f32_16x16x32_bf16(vv1[f], pf1, c_o[f], 0, 0, 0);
        }
    }

    // in-wave lsum reduce (combine 4 quads -> per-row partial)
    lsum += __shfl_xor(lsum, 16);
    lsum += __shfl_xor(lsum, 32);
    if (quad == 0) Ls[w][li] = lsum;

    __syncthreads();   // all P reads everywhere done before Or overwrites

    // write O partials: lane holds dims {f*16+quad*4+rr} for q-row li
    {
        float* orw = &Or[w * 1088];
#pragma unroll
        for (int f = 0; f < 4; ++f)
            *(f4v*)&orw[li * 68 + f * 16 + quad * 4] = c_o[f];
    }

    __syncthreads();

    // reduce 4 wave-partials; thread t -> (row = t>>4, dims (t&15)*4 .. +3)
    {
        const int row = tid >> 4;
        const int c4 = (tid & 15) << 2;
        f4v s = (f4v){0.f, 0.f, 0.f, 0.f};
        float lt = 0.f;
#pragma unroll
        for (int w2 = 0; w2 < 4; ++w2) {
            f4v p = *(const f4v*)&Or[w2 * 1088 + row * 68 + c4];
            s[0] += p[0]; s[1] += p[1]; s[2] += p[2]; s[3] += p[3];
            lt += Ls[w2][row];
        }
        const float inv = 1.0f / lt;
        *(float4*)(out + (base + (qi << 4) + row) * HS + c4) =
            make_float4(s[0] * inv, s[1] * inv, s[2] * inv, s[3] * inv);
    }
}

extern "C" void kernel_launch(void* const* d_in, const int* in_sizes, int n_in,
                              void* d_out, int out_size, void* d_ws, size_t ws_size,
                              hipStream_t stream) {
    const float* x  = (const float*)d_in[0];
    const float* Wk = (const float*)d_in[1];
    const float* bk = (const float*)d_in[2];
    const float* Wq = (const float*)d_in[3];
    const float* bq = (const float*)d_in[4];
    const float* Wv = (const float*)d_in[5];
    const float* bv = (const float*)d_in[6];
    float* outp = (float*)d_out;

    const size_t elems = (size_t)16 * TSEQ * HS;  // 2M per tensor
    unsigned short* qbuf = (unsigned short*)d_ws;
    unsigned short* kbuf = qbuf + elems;
    unsigned short* vbuf = kbuf + elems;          // transposed [b][dim][t]
    unsigned short* wtb  = vbuf + elems;          // [3][64][128] bf16

    wconv<<<48, 256, 0, stream>>>(Wq, Wk, Wv, wtb);
    qkv<<<6144, 64, 0, stream>>>(x, wtb, bq, bk, bv, qbuf, kbuf, vbuf);
    attn<<<2048, 256, 0, stream>>>(qbuf, kbuf, vbuf, outp);
}

// Round 8
// 114.413 us; speedup vs baseline: 1.3677x; 1.3677x over previous
//
#include <hip/hip_runtime.h>
#include <hip/hip_bf16.h>
#include <math.h>

#define HS 64
#define NE 128
#define TSEQ 2048

typedef short s8v __attribute__((ext_vector_type(8)));   // 8 bf16 (4 VGPRs) MFMA A/B frag
typedef float f4v __attribute__((ext_vector_type(4)));   // 4 fp32 MFMA C/D frag

__device__ __forceinline__ unsigned short f2bf(float f) {
    unsigned int u = __float_as_uint(f);
    u += 0x7FFFu + ((u >> 16) & 1u);   // RNE (no NaN inputs here)
    return (unsigned short)(u >> 16);
}

__device__ __forceinline__ unsigned int pkbf(float a, float b) {
    union { __hip_bfloat162 h; unsigned int u; } cv;
    cv.h = __float22bfloat162_rn(make_float2(a, b));
    return cv.u;
}

__device__ __forceinline__ s8v mk_s8v(unsigned int a, unsigned int b,
                                      unsigned int c, unsigned int d) {
    union { unsigned int u[4]; s8v v; } cv;
    cv.u[0] = a; cv.u[1] = b; cv.u[2] = c; cv.u[3] = d;
    return cv.v;
}

// raw v_exp_f32 (2^x). exp2f without -ffast-math is an OCML call — critical-path killer.
__device__ __forceinline__ float fexp2(float x) {
    float r;
    asm("v_exp_f32 %0, %1" : "=v"(r) : "v"(x));
    return r;
}

// async global->LDS, 16B per lane (dest = wave-uniform base + lane*16).
__device__ __forceinline__ void glds16(const unsigned short* g, unsigned short* l) {
    __builtin_amdgcn_global_load_lds(
        (const __attribute__((address_space(1))) unsigned int*)g,
        (__attribute__((address_space(3))) unsigned int*)l,
        16, 0, 0);
}

// ---------------- W -> bf16, transposed wt[mat][n][k], q pre-scaled ----------------
__global__ __launch_bounds__(256) void wconv(
    const float* __restrict__ Wq, const float* __restrict__ Wk,
    const float* __restrict__ Wv, unsigned short* __restrict__ wt)
{
    const int o0 = (blockIdx.x * 256 + threadIdx.x) * 2;   // 24576 elems total
    const int mat = o0 >> 13;
    const int n = (o0 >> 7) & 63;
    const int k = o0 & 127;        // even
    const float* W = (mat == 0) ? Wq : (mat == 1) ? Wk : Wv;
    const float s = (mat == 0) ? 0.18033688f : 1.0f;   // 64^-0.5 * log2(e)
    unsigned int lo = f2bf(W[k * HS + n] * s);
    unsigned int hi = f2bf(W[(k + 1) * HS + n] * s);
    *(unsigned int*)(wt + o0) = lo | (hi << 16);
}

// ---------------- QKV projection (R6 version: bf16 MFMA, W in LDS) ----------------
__global__ __launch_bounds__(256) void qkv(
    const float* __restrict__ x, const unsigned short* __restrict__ wt,
    const float* __restrict__ bq, const float* __restrict__ bk,
    const float* __restrict__ bv,
    unsigned short* __restrict__ qo, unsigned short* __restrict__ ko,
    unsigned short* __restrict__ vt)
{
    __shared__ __align__(16) unsigned short Ws[192 * 136];  // 51 KB; reused for transpose

    const int tid = threadIdx.x;
    const int w = tid >> 6;
    const int lane = tid & 63;
    const int quad = lane >> 4;
    const int li = lane & 15;
    const size_t blk0 = (size_t)blockIdx.x * 64;
    const size_t row0w = blk0 + (size_t)w * 16;

#pragma unroll
    for (int p = 0; p < 12; ++p) {
        const int idx = p * 256 + tid;
        const int n = idx >> 4;
        const int c = idx & 15;
        s8v d = *(const s8v*)(wt + idx * 8);
        *(s8v*)&Ws[n * 136 + c * 8] = d;
    }

    s8v a[4];
    const float* xr = x + (row0w + li) * NE + quad * 8;
#pragma unroll
    for (int ks = 0; ks < 4; ++ks) {
        float4 f0 = *(const float4*)(xr + ks * 32);
        float4 f1 = *(const float4*)(xr + ks * 32 + 4);
        a[ks] = mk_s8v(pkbf(f0.x, f0.y), pkbf(f0.z, f0.w),
                       pkbf(f1.x, f1.y), pkbf(f1.z, f1.w));
    }

    __syncthreads();

    f4v acc[12];
#pragma unroll
    for (int nt = 0; nt < 12; ++nt) acc[nt] = (f4v){0.f, 0.f, 0.f, 0.f};

#pragma unroll
    for (int nt = 0; nt < 12; ++nt) {
        const unsigned short* wr = &Ws[(nt * 16 + li) * 136 + quad * 8];
#pragma unroll
        for (int ks = 0; ks < 4; ++ks) {
            s8v bfr = *(const s8v*)(wr + ks * 32);
            acc[nt] = __builtin_amdgcn_mfma_f32_16x16x32_bf16(a[ks], bfr, acc[nt], 0, 0, 0);
        }
    }

    const size_t bidx = row0w >> 11;
    const size_t trow0 = row0w & 2047;
#pragma unroll
    for (int nt = 0; nt < 4; ++nt) {
        const float bias = bv[nt * 16 + li];
        unsigned int lo = pkbf(acc[nt + 8][0] + bias, acc[nt + 8][1] + bias);
        unsigned int hi = pkbf(acc[nt + 8][2] + bias, acc[nt + 8][3] + bias);
        *(uint2*)(vt + (bidx * HS + nt * 16 + li) * TSEQ + trow0 + quad * 4) =
            make_uint2(lo, hi);
    }

    __syncthreads();

    float* Qt = (float*)Ws;            // [64][68]
    float* Kt = Qt + 64 * 68;
    const float sq = 0.18033688f;
    const int lrow0 = w * 16 + quad * 4;
#pragma unroll
    for (int nt = 0; nt < 4; ++nt) {
        const int col = nt * 16 + li;
        const float bq_ = bq[col] * sq;
        const float bk_ = bk[col];
#pragma unroll
        for (int r = 0; r < 4; ++r) {
            Qt[(lrow0 + r) * 68 + col] = acc[nt][r] + bq_;
            Kt[(lrow0 + r) * 68 + col] = acc[nt + 4][r] + bk_;
        }
    }

    __syncthreads();

    const int row = tid >> 2;
    const int seg = tid & 3;
    {
        const float* src = &Qt[row * 68 + seg * 16];
        float4 f0 = *(const float4*)src;
        float4 f1 = *(const float4*)(src + 4);
        float4 f2 = *(const float4*)(src + 8);
        float4 f3 = *(const float4*)(src + 12);
        s8v d0 = mk_s8v(pkbf(f0.x, f0.y), pkbf(f0.z, f0.w), pkbf(f1.x, f1.y), pkbf(f1.z, f1.w));
        s8v d1 = mk_s8v(pkbf(f2.x, f2.y), pkbf(f2.z, f2.w), pkbf(f3.x, f3.y), pkbf(f3.z, f3.w));
        unsigned short* dst = qo + (blk0 + row) * HS + seg * 16;
        *(s8v*)dst = d0;
        *(s8v*)(dst + 8) = d1;
    }
    {
        const float* src = &Kt[row * 68 + seg * 16];
        float4 f0 = *(const float4*)src;
        float4 f1 = *(const float4*)(src + 4);
        float4 f2 = *(const float4*)(src + 8);
        float4 f3 = *(const float4*)(src + 12);
        s8v d0 = mk_s8v(pkbf(f0.x, f0.y), pkbf(f0.z, f0.w), pkbf(f1.x, f1.y), pkbf(f1.z, f1.w));
        s8v d1 = mk_s8v(pkbf(f2.x, f2.y), pkbf(f2.z, f2.w), pkbf(f3.x, f3.y), pkbf(f3.z, f3.w));
        unsigned short* dst = ko + (blk0 + row) * HS + seg * 16;
        *(s8v*)dst = d0;
        *(s8v*)(dst + 8) = d1;
    }
}

// ---------------- Flash attention, balanced chunks + partials ----------------
// Work unit = (batch, q64-tile qt, chunk of <=8 key-tile64s). 80 chunks/batch,
// 1280 blocks (4 waves, 64 q-rows, R5-style glds double-buffered K/V staging).
// No-max exp2 softmax => chunks additive: single-chunk q-tiles (qt<8) write out
// directly; others write fp32 O-partial + lsum, combined by attn_reduce.
__global__ __launch_bounds__(256) void attn_main(
    const unsigned short* __restrict__ qb,
    const unsigned short* __restrict__ kb,
    const unsigned short* __restrict__ vtb,
    float* __restrict__ out, float* __restrict__ pbuf, float* __restrict__ lsbuf)
{
    __shared__ unsigned short Ks[2][64 * 64];
    __shared__ unsigned short Vs[2][64 * 64];
    __shared__ __align__(16) unsigned short Ps[4][1024];   // granule-transposed P

    const int tid = threadIdx.x;
    const int w = tid >> 6;
    const int lane = tid & 63;
    const int quad = lane >> 4;
    const int li = lane & 15;

    const int id = blockIdx.x;
    const int b = id / 80;
    const int u = 79 - (id - b * 80);   // big chunks first
    int qt, c, nc;
    if (u < 8)       { qt = u;                 c = 0;            nc = 1; }
    else if (u < 24) { qt = 8 + ((u - 8) >> 1);  c = (u - 8) & 1;  nc = 2; }
    else if (u < 48) { qt = 16 + (u - 24) / 3;   c = (u - 24) % 3; nc = 3; }
    else             { qt = 24 + ((u - 48) >> 2); c = (u - 48) & 3; nc = 4; }
    const int tb = c * 8;
    const int te_ = tb + 8;
    const int te = (te_ < qt + 1) ? te_ : (qt + 1);

    const size_t base = (size_t)b * TSEQ;
    const int t0 = qt << 6;
    const int qrow = t0 + w * 16 + li;

    // Q B-frags (scale*log2e pre-folded)
    const unsigned short* qrp = qb + (base + qrow) * HS + quad * 8;
    s8v qf0 = *(const s8v*)qrp;
    s8v qf1 = *(const s8v*)(qrp + 32);

    // staging geometry (verified R5): wave w rows [w*8,w*8+8) and +32
    const int rA = w * 8 + (lane >> 3);
    const int csw = (lane & 7) ^ (rA & 7);
    const unsigned short* kgA = kb + (base + rA) * HS + csw * 8;
    const unsigned short* kgB = kgA + 32 * HS;
    const unsigned short* vgA = vtb + ((size_t)b * HS + rA) * TSEQ + csw * 8;
    const unsigned short* vgB = vgA + 32 * TSEQ;
    const int ldsA = w * 512 + lane * 8;
    const int ldsB = 2048 + w * 512 + lane * 8;

    // prologue: stage tile tb -> buf 0
    glds16(kgA + (size_t)tb * 4096, &Ks[0][ldsA]);
    glds16(kgB + (size_t)tb * 4096, &Ks[0][ldsB]);
    glds16(vgA + (size_t)tb * 64,   &Vs[0][ldsA]);
    glds16(vgB + (size_t)tb * 64,   &Vs[0][ldsB]);

    f4v c_o[4];
#pragma unroll
    for (int f = 0; f < 4; ++f) c_o[f] = (f4v){0.f, 0.f, 0.f, 0.f};
    float lsum = 0.f;

    char* pbse = (char*)&Ps[w][0];
    const int swz0 = (quad ^ (li & 7)) * 8;
    const int swz1 = ((4 + quad) ^ (li & 7)) * 8;

    __syncthreads();

    for (int tl = tb; tl < te; ++tl) {
        const int bi = (tl - tb) & 1;
        if (tl + 1 < te) {
            const int nb = bi ^ 1;
            glds16(kgA + (size_t)(tl + 1) * 4096, &Ks[nb][ldsA]);
            glds16(kgB + (size_t)(tl + 1) * 4096, &Ks[nb][ldsB]);
            glds16(vgA + (size_t)(tl + 1) * 64,   &Vs[nb][ldsA]);
            glds16(vgB + (size_t)(tl + 1) * 64,   &Vs[nb][ldsB]);
        }
        const unsigned short* Kc = &Ks[bi][0];
        const unsigned short* Vc = &Vs[bi][0];
        const bool diag = (tl == qt);

        // ---- S^T = K·Q^T, exp2 softmax (raw v_exp_f32) ----
        float pr[4][4];
        float rs = 0.f;
#pragma unroll
        for (int kt = 0; kt < 4; ++kt) {
            const unsigned short* krow = Kc + (kt * 16 + li) * 64;
            s8v k0 = *(const s8v*)(krow + swz0);
            s8v k1 = *(const s8v*)(krow + swz1);
            f4v cst = (f4v){0.f, 0.f, 0.f, 0.f};
            cst = __builtin_amdgcn_mfma_f32_16x16x32_bf16(k0, qf0, cst, 0, 0, 0);
            cst = __builtin_amdgcn_mfma_f32_16x16x32_bf16(k1, qf1, cst, 0, 0, 0);
            if (diag) {
                const int key0 = (tl << 6) + kt * 16 + quad * 4;
#pragma unroll
                for (int rr = 0; rr < 4; ++rr)
                    if (key0 + rr > qrow) cst[rr] = -INFINITY;
            }
#pragma unroll
            for (int rr = 0; rr < 4; ++rr) {
                pr[kt][rr] = fexp2(cst[rr]);
                rs += pr[kt][rr];
            }
        }
        lsum += rs;   // per-lane partial; quad-reduced in epilogue

        // ---- P -> LDS (granule-transposed, conflict-free; verified R7) ----
#pragma unroll
        for (int kt = 0; kt < 4; ++kt) {
            *(uint2*)(pbse + (kt * 2 + (quad >> 1)) * 256 + li * 16 + (quad & 1) * 8) =
                make_uint2(pkbf(pr[kt][0], pr[kt][1]), pkbf(pr[kt][2], pr[kt][3]));
        }
        s8v pf0 = *(const s8v*)(pbse + lane * 16);
        s8v pf1 = *(const s8v*)(pbse + 1024 + lane * 16);

        // ---- O^T += V^T · P^T ----
#pragma unroll
        for (int f = 0; f < 4; ++f) {
            const unsigned short* vrow = Vc + (f * 16 + li) * 64;
            s8v v0 = *(const s8v*)(vrow + swz0);
            s8v v1 = *(const s8v*)(vrow + swz1);
            c_o[f] = __builtin_amdgcn_mfma_f32_16x16x32_bf16(v0, pf0, c_o[f], 0, 0, 0);
            c_o[f] = __builtin_amdgcn_mfma_f32_16x16x32_bf16(v1, pf1, c_o[f], 0, 0, 0);
        }

        __syncthreads();   // buf[bi] reads done; prefetch drained
    }

    // per-row lsum (sum the 4 quads)
    lsum += __shfl_xor(lsum, 16);
    lsum += __shfl_xor(lsum, 32);

    if (nc == 1) {
        const float inv = 1.0f / lsum;
        float* orow = out + (base + qrow) * HS + quad * 4;
#pragma unroll
        for (int f = 0; f < 4; ++f) {
            f4v res = c_o[f];
            res[0] *= inv; res[1] *= inv; res[2] *= inv; res[3] *= inv;
            *(f4v*)(orow + f * 16) = res;
        }
    } else {
        const int local = (qt < 16) ? (qt - 8) * 2 + c
                        : (qt < 24) ? 16 + (qt - 16) * 3 + c
                                    : 40 + (qt - 24) * 4 + c;
        const int pidx = b * 72 + local;
        float* pc = pbuf + (size_t)pidx * 4096 + (w * 16 + li) * 64;
#pragma unroll
        for (int f = 0; f < 4; ++f)
            *(f4v*)(pc + f * 16 + quad * 4) = c_o[f];
        if (quad == 0)
            lsbuf[(size_t)pidx * 64 + w * 16 + li] = lsum;
    }
}

// ---------------- Partial combine + normalize (qt >= 8) ----------------
__global__ __launch_bounds__(256) void attn_reduce(
    const float* __restrict__ pbuf, const float* __restrict__ lsbuf,
    float* __restrict__ out)
{
    const int g = blockIdx.x;            // 384 = 16 batches * 24 q-tiles
    const int b = g / 24;
    const int r = g - b * 24;
    int qt, lbase, nc;
    if (r < 8)       { qt = 8 + r;        lbase = 2 * r;            nc = 2; }
    else if (r < 16) { qt = 16 + (r - 8); lbase = 16 + 3 * (r - 8); nc = 3; }
    else             { qt = 24 + (r - 16); lbase = 40 + 4 * (r - 16); nc = 4; }
    const int pidx0 = b * 72 + lbase;

    const int tid = threadIdx.x;
    const int row = tid >> 2;
    const int seg = tid & 3;

    float4 acc[4];
#pragma unroll
    for (int j = 0; j < 4; ++j) acc[j] = make_float4(0.f, 0.f, 0.f, 0.f);
    float ls = 0.f;

    for (int cc = 0; cc < nc; ++cc) {
        const float* pc = pbuf + (size_t)(pidx0 + cc) * 4096 + row * 64 + seg * 16;
#pragma unroll
        for (int j = 0; j < 4; ++j) {
            float4 v = *(const float4*)(pc + j * 4);
            acc[j].x += v.x; acc[j].y += v.y; acc[j].z += v.z; acc[j].w += v.w;
        }
        ls += lsbuf[(size_t)(pidx0 + cc) * 64 + row];
    }
    const float inv = 1.0f / ls;
    float* orow = out + ((size_t)b * TSEQ + (qt << 6) + row) * HS + seg * 16;
#pragma unroll
    for (int j = 0; j < 4; ++j) {
        *(float4*)(orow + j * 4) = make_float4(acc[j].x * inv, acc[j].y * inv,
                                               acc[j].z * inv, acc[j].w * inv);
    }
}

extern "C" void kernel_launch(void* const* d_in, const int* in_sizes, int n_in,
                              void* d_out, int out_size, void* d_ws, size_t ws_size,
                              hipStream_t stream) {
    const float* x  = (const float*)d_in[0];
    const float* Wk = (const float*)d_in[1];
    const float* bk = (const float*)d_in[2];
    const float* Wq = (const float*)d_in[3];
    const float* bq = (const float*)d_in[4];
    const float* Wv = (const float*)d_in[5];
    const float* bv = (const float*)d_in[6];
    float* outp = (float*)d_out;

    const size_t elems = (size_t)16 * TSEQ * HS;  // 2M per tensor
    unsigned short* qbuf = (unsigned short*)d_ws;
    unsigned short* kbuf = qbuf + elems;
    unsigned short* vbuf = kbuf + elems;          // transposed [b][dim][t]
    unsigned short* wtb  = vbuf + elems;          // [3][64][128] bf16
    float* pbuf  = (float*)(wtb + 32768);         // [1152][64][64] fp32 partials
    float* lsbuf = pbuf + (size_t)1152 * 4096;    // [1152][64] lsums

    wconv<<<48, 256, 0, stream>>>(Wq, Wk, Wv, wtb);
    qkv<<<512, 256, 0, stream>>>(x, wtb, bq, bk, bv, qbuf, kbuf, vbuf);
    attn_main<<<1280, 256, 0, stream>>>(qbuf, kbuf, vbuf, outp, pbuf, lsbuf);
    attn_reduce<<<384, 256, 0, stream>>>(pbuf, lsbuf, outp);
}